// Round 3
// baseline (589.484 us; speedup 1.0000x reference)
//
#include <hip/hip_runtime.h>
#include <hip/hip_bf16.h>

// out[b,i,f] = softmax_j(noise[b,i,:]) @ feat[b,j,f];  B=16,L=2048,F=512 fp32.
// exp w/o max-subtraction -> single-pass (exp(noise) @ feat_bf16) / rowsum.
// K1: feat -> bf16 panels [b][k/32][n][k%32] (32 MiB ws).
// K2: TM=128 x full-F block (grid=256, 1 block/CU), BK=64 per barrier (2 MFMA
// sub-steps), A via 36KB dbuf LDS, B-frags straight from L2-resident panels
// into VGPRs (coalesced 1KB/wave reads, no LDS, no DMA-drain coupling), noise
// prefetched cross-iteration (issued top of iter kb for kb+2) so the
// compiler's pre-barrier vmcnt(0) drain never eats an HBM latency.

#define NB 16
#define SL 2048
#define NF 512
#define TM 128
#define BK 64
#define NKB (SL / BK)        // 32 barrier iters
#define NPKB (SL / 32)       // 64 panel k-blocks (panels stay 32-k)
#define NT 512
#define ASTRIDE 72           // 64 + 8 shorts pad -> 144B rows, 2-way banks

typedef __bf16 bf16x8 __attribute__((ext_vector_type(8)));
typedef float  f32x4  __attribute__((ext_vector_type(4)));

__device__ __forceinline__ unsigned int f2bf(float x) {
    union { float f; unsigned int u; } v; v.f = x;
    return (v.u + 0x7FFFu + ((v.u >> 16) & 1u)) >> 16;   // RNE bf16, high 16
}

// ---------------------------------------------------------------------------
// Kernel 1: FeatP[b][kb][n][ki] = bf16(feat[b][kb*32+ki][n])   (panel 512x32)
// ---------------------------------------------------------------------------
__global__ __launch_bounds__(256, 4)
void feat_panelize(const float* __restrict__ feat, unsigned short* __restrict__ featP) {
    __shared__ unsigned short Lt[32][270];   // 540B rows: odd bank step
    const int t  = threadIdx.x;
    const int n0 = blockIdx.x * 256;
    const int kb = blockIdx.y;
    const int b  = blockIdx.z;
    const float* src = feat + ((size_t)b * SL + (size_t)kb * 32) * NF + n0;
    const int j  = t >> 3;
    const int c0 = (t & 7) << 2;
    #pragma unroll
    for (int c = 0; c < 8; ++c) {
        const float4 v = *(const float4*)(src + (size_t)j * NF + c0 + (c << 5));
        unsigned short* p = &Lt[j][c0 + (c << 5)];
        p[0] = (unsigned short)f2bf(v.x); p[1] = (unsigned short)f2bf(v.y);
        p[2] = (unsigned short)f2bf(v.z); p[3] = (unsigned short)f2bf(v.w);
    }
    __syncthreads();
    unsigned int w[16];
    #pragma unroll
    for (int m = 0; m < 16; ++m)
        w[m] = (unsigned int)Lt[2 * m][t] | ((unsigned int)Lt[2 * m + 1][t] << 16);
    unsigned short* dst = featP + ((size_t)(b * NPKB + kb) * NF + (size_t)(n0 + t)) * 32;
    #pragma unroll
    for (int c = 0; c < 4; ++c)
        *(uint4*)(dst + (c << 3)) = *(const uint4*)&w[c << 2];
}

// ---------------------------------------------------------------------------
// Kernel 2: fused exp-softmax + GEMM.
// ---------------------------------------------------------------------------

// One BK=64 barrier iteration. CONS holds noise(kb+1) (loaded >=1 iter ago),
// LOADB receives noise(kb+2) issued at the TOP so the pre-barrier vmcnt(0)
// drain finds it (nearly) complete.
#define FA_BODY(KB, CUR, CONS, LOADB)                                          \
    {                                                                          \
        const int kb_ = (KB);                                                  \
        const int nxt_ = (CUR) ^ 1;                                            \
        if (kb_ + 2 < NKB) {                                                   \
            const float* np_ = a_src + (size_t)(kb_ + 2) * BK;                 \
            _Pragma("unroll")                                                  \
            for (int c = 0; c < 4; ++c) LOADB[c] = *(const float4*)(np_ + (c << 2)); \
        }                                                                      \
        const unsigned short* pan_ = featB + (size_t)(kb_ << 1) * (NF * 32);   \
        bf16x8 bfr0[4], bfr1[4];                                               \
        _Pragma("unroll")                                                      \
        for (int ni = 0; ni < 4; ++ni)                                         \
            bfr0[ni] = *(const bf16x8*)(pan_ + (size_t)(((wv << 6) + (ni << 4) + fm) << 5) + (fq << 3)); \
        _Pragma("unroll")                                                      \
        for (int ni = 0; ni < 4; ++ni)                                         \
            bfr1[ni] = *(const bf16x8*)(pan_ + NF * 32 + (size_t)(((wv << 6) + (ni << 4) + fm) << 5) + (fq << 3)); \
        _Pragma("unroll")                                                      \
        for (int mi = 0; mi < 8; ++mi) {                                       \
            const bf16x8 af_ = *(const bf16x8*)&As[CUR][(mi << 4) + fm][fq << 3]; \
            _Pragma("unroll")                                                  \
            for (int ni = 0; ni < 4; ++ni)                                     \
                acc[mi][ni] = __builtin_amdgcn_mfma_f32_16x16x32_bf16(af_, bfr0[ni], acc[mi][ni], 0, 0, 0); \
        }                                                                      \
        if (kb_ + 1 < NKB) {                                                   \
            const float e0_ = __expf(CONS[0].x), e1_ = __expf(CONS[0].y);      \
            const float e2_ = __expf(CONS[0].z), e3_ = __expf(CONS[0].w);      \
            const float e4_ = __expf(CONS[1].x), e5_ = __expf(CONS[1].y);      \
            const float e6_ = __expf(CONS[1].z), e7_ = __expf(CONS[1].w);      \
            const float e8_ = __expf(CONS[2].x), e9_ = __expf(CONS[2].y);      \
            const float ea_ = __expf(CONS[2].z), eb_ = __expf(CONS[2].w);      \
            const float ec_ = __expf(CONS[3].x), ed_ = __expf(CONS[3].y);      \
            const float ee_ = __expf(CONS[3].z), ef_ = __expf(CONS[3].w);      \
            rowsum += (((e0_+e1_)+(e2_+e3_)) + ((e4_+e5_)+(e6_+e7_)))          \
                    + (((e8_+e9_)+(ea_+eb_)) + ((ec_+ed_)+(ee_+ef_)));         \
            uint4 q0_, q1_;                                                    \
            q0_.x = f2bf(e0_) | (f2bf(e1_) << 16); q0_.y = f2bf(e2_) | (f2bf(e3_) << 16); \
            q0_.z = f2bf(e4_) | (f2bf(e5_) << 16); q0_.w = f2bf(e6_) | (f2bf(e7_) << 16); \
            q1_.x = f2bf(e8_) | (f2bf(e9_) << 16); q1_.y = f2bf(ea_) | (f2bf(eb_) << 16); \
            q1_.z = f2bf(ec_) | (f2bf(ed_) << 16); q1_.w = f2bf(ee_) | (f2bf(ef_) << 16); \
            *(uint4*)&As[nxt_][ar][ac] = q0_;                                  \
            *(uint4*)&As[nxt_][ar][ac + 8] = q1_;                              \
        }                                                                      \
        _Pragma("unroll")                                                      \
        for (int mi = 0; mi < 8; ++mi) {                                       \
            const bf16x8 af_ = *(const bf16x8*)&As[CUR][(mi << 4) + fm][32 + (fq << 3)]; \
            _Pragma("unroll")                                                  \
            for (int ni = 0; ni < 4; ++ni)                                     \
                acc[mi][ni] = __builtin_amdgcn_mfma_f32_16x16x32_bf16(af_, bfr1[ni], acc[mi][ni], 0, 0, 0); \
        }                                                                      \
        __syncthreads();                                                       \
    }

__global__ __launch_bounds__(NT, 2)
void frame_augment(const float* __restrict__ noise,
                   const unsigned short* __restrict__ featP,
                   float* __restrict__ out) {
    __shared__ __align__(16) unsigned short As[2][TM][ASTRIDE];   // 36 KB
    __shared__ float part[TM][4];
    __shared__ float linv[TM];

    const int tid  = threadIdx.x;
    const int lane = tid & 63;
    const int wv   = tid >> 6;                          // 0..7 -> 64-col slice
    const int n    = blockIdx.x;                        // 0..255
    const int b    = ((n & 7) << 1) | ((n >> 3) & 1);   // XCD n%8 hosts b=2x,2x+1
    const int i0   = (n >> 4) * TM;

    const float* noise_b = noise + ((size_t)b * SL + i0) * SL;
    const unsigned short* featB = featP + (size_t)b * NPKB * NF * 32;
    float* out_b = out + ((size_t)b * SL + i0) * NF;

    const int ar = tid >> 2;                 // 0..127 A row
    const int ac = (tid & 3) << 4;           // col base in shorts/floats (16 wide)
    const int fm = lane & 15;
    const int fq = lane >> 4;

    f32x4 acc[8][4];
    #pragma unroll
    for (int mi = 0; mi < 8; ++mi)
        #pragma unroll
        for (int ni = 0; ni < 4; ++ni)
            acc[mi][ni] = (f32x4){0.f, 0.f, 0.f, 0.f};

    float rowsum = 0.f;
    const float* a_src = noise_b + (size_t)ar * SL + ac;

    float4 nvA[4], nvB[4];
    // ---- prologue: As[0] <- exp(noise tile 0); nvA <- noise tile 1
    #pragma unroll
    for (int c = 0; c < 4; ++c) nvB[c] = *(const float4*)(a_src + (c << 2));
    {
        const float e0 = __expf(nvB[0].x), e1 = __expf(nvB[0].y);
        const float e2 = __expf(nvB[0].z), e3 = __expf(nvB[0].w);
        const float e4 = __expf(nvB[1].x), e5 = __expf(nvB[1].y);
        const float e6 = __expf(nvB[1].z), e7 = __expf(nvB[1].w);
        const float e8 = __expf(nvB[2].x), e9 = __expf(nvB[2].y);
        const float ea = __expf(nvB[2].z), eb = __expf(nvB[2].w);
        const float ec = __expf(nvB[3].x), ed = __expf(nvB[3].y);
        const float ee = __expf(nvB[3].z), ef = __expf(nvB[3].w);
        rowsum += (((e0+e1)+(e2+e3)) + ((e4+e5)+(e6+e7)))
                + (((e8+e9)+(ea+eb)) + ((ec+ed)+(ee+ef)));
        uint4 q0, q1;
        q0.x = f2bf(e0) | (f2bf(e1) << 16); q0.y = f2bf(e2) | (f2bf(e3) << 16);
        q0.z = f2bf(e4) | (f2bf(e5) << 16); q0.w = f2bf(e6) | (f2bf(e7) << 16);
        q1.x = f2bf(e8) | (f2bf(e9) << 16); q1.y = f2bf(ea) | (f2bf(eb) << 16);
        q1.z = f2bf(ec) | (f2bf(ed) << 16); q1.w = f2bf(ee) | (f2bf(ef) << 16);
        *(uint4*)&As[0][ar][ac] = q0;
        *(uint4*)&As[0][ar][ac + 8] = q1;
    }
    #pragma unroll
    for (int c = 0; c < 4; ++c) nvA[c] = *(const float4*)(a_src + BK + (c << 2));
    __syncthreads();

    // ---- main loop, manual 2x unroll so nv buffer choice is compile-time
    for (int kbp = 0; kbp < NKB; kbp += 2) {
        FA_BODY(kbp,     0, nvA, nvB)
        FA_BODY(kbp + 1, 1, nvB, nvA)
    }

    // ---- softmax denominator
    part[ar][tid & 3] = rowsum;
    __syncthreads();
    if (tid < TM) {
        const float* q = part[tid];
        linv[tid] = 1.0f / ((q[0] + q[1]) + (q[2] + q[3]));
    }
    __syncthreads();

    // ---- epilogue: D[row=(lane>>4)*4+r][col=lane&15] per 16x16 tile
    #pragma unroll
    for (int mi = 0; mi < 8; ++mi) {
        #pragma unroll
        for (int r = 0; r < 4; ++r) {
            const int row = mi * 16 + (fq << 2) + r;
            const float sc = linv[row];
            float* orow = out_b + (size_t)row * NF + (wv << 6) + fm;
            #pragma unroll
            for (int ni = 0; ni < 4; ++ni)
                orow[ni * 16] = acc[mi][ni][r] * sc;
        }
    }
}

extern "C" void kernel_launch(void* const* d_in, const int* in_sizes, int n_in,
                              void* d_out, int out_size, void* d_ws, size_t ws_size,
                              hipStream_t stream) {
    (void)in_sizes; (void)n_in; (void)out_size; (void)ws_size;
    const float* feat  = (const float*)d_in[0];
    const float* noise = (const float*)d_in[1];
    float* outp = (float*)d_out;
    unsigned short* featP = (unsigned short*)d_ws;   // 16*64*512*32*2 = 32 MiB

    feat_panelize<<<dim3(NF / 256, NPKB, NB), 256, 0, stream>>>(feat, featP);
    frame_augment<<<dim3(SL / TM * NB), NT, 0, stream>>>(noise, featP, outp);
}